// Round 1
// baseline (382.343 us; speedup 1.0000x reference)
//
#include <hip/hip_runtime.h>

#define NN 4096
#define CC 32
#define TT 12
#define BB 4
#define BT 48          // BB*TT
#define NC 1536        // BT*CC
#define MAXD 192       // mean degree ~82, P(deg>192) astronomically small
#define PAD 36         // padded row stride for LDS mix staging (bank-conflict free, 16B-aligned)

__device__ __forceinline__ float bf2f(unsigned short h) {
  return __uint_as_float(((unsigned int)h) << 16);
}
__device__ __forceinline__ unsigned short f2bf(float f) {
  unsigned int u = __float_as_uint(f);
  return (unsigned short)((u + 0x7FFFu + ((u >> 16) & 1u)) >> 16);  // RNE
}
__device__ __forceinline__ float blo(unsigned int w) { return __uint_as_float(w << 16); }
__device__ __forceinline__ float bhi(unsigned int w) { return __uint_as_float(w & 0xFFFF0000u); }

// ---- dtype sniffing: bf16 halfwords have plausible exponent fields; fp32 low
// mantissa halfwords are ~uniform. 256 words of weight: bf16 -> ~256 hits,
// fp32 -> ~50 hits. Threshold 150.
__global__ void k_detect(const unsigned int* __restrict__ w, int* __restrict__ flag) {
  if (blockIdx.x == 0 && threadIdx.x == 0) {
    int hits = 0;
    for (int i = 0; i < 256; ++i) {
      unsigned int lo = w[i] & 0xFFFFu;
      unsigned int e = (lo >> 7) & 0xFFu;
      if (e >= 90u && e <= 141u) ++hits;
    }
    *flag = (hits >= 150) ? 1 : 0;
  }
}

// ---- per-row adjacency compaction + degree + d^-1/2 (self-loops included)
template<int BF16>
__global__ __launch_bounds__(256) void k_build(const void* __restrict__ adjv,
                                               unsigned short* __restrict__ colidx,
                                               int* __restrict__ deg, float* __restrict__ dis,
                                               const int* __restrict__ flag) {
  if ((*flag != 0) != (BF16 != 0)) return;
  __shared__ int cnt;
  int m = blockIdx.x;
  if (threadIdx.x == 0) cnt = 0;
  __syncthreads();
  if (BF16) {
    const unsigned short* row = (const unsigned short*)adjv + (size_t)m * NN;
    for (int i = threadIdx.x; i < NN; i += 256) {
      if (row[i] != 0) {
        int p = atomicAdd(&cnt, 1);
        if (p < MAXD) colidx[m * MAXD + p] = (unsigned short)i;
      }
    }
  } else {
    const unsigned int* row = (const unsigned int*)adjv + (size_t)m * NN;
    for (int i = threadIdx.x; i < NN; i += 256) {
      if (row[i] != 0) {
        int p = atomicAdd(&cnt, 1);
        if (p < MAXD) colidx[m * MAXD + p] = (unsigned short)i;
      }
    }
  }
  __syncthreads();
  if (threadIdx.x == 0) {
    int d = cnt < MAXD ? cnt : MAXD;
    deg[m] = d;
    dis[m] = d > 0 ? (float)(1.0 / sqrt((double)d)) : 0.0f;
  }
}

// ---- x[b][c][n][t] -> H[n][bt][c] (bf16), coalesced 8B writes
template<int BF16>
__global__ __launch_bounds__(256) void k_trans(const void* __restrict__ xv,
                                               unsigned short* __restrict__ H,
                                               const int* __restrict__ flag) {
  if ((*flag != 0) != (BF16 != 0)) return;
  int i = blockIdx.x * 256 + threadIdx.x;   // i < NN*BT*8
  int c4 = (i & 7) << 2;
  int r  = i >> 3;            // r = n*BT + bt
  int bt = r % BT;
  int b  = bt / TT;
  int t  = bt - b * TT;
  int n  = r / BT;
  const size_t S = (size_t)NN * TT;
  size_t src = ((((size_t)b * CC + c4) * NN + n) * TT + t);
  ushort4 v;
  if (BF16) {
    const unsigned short* x = (const unsigned short*)xv;
    v.x = x[src]; v.y = x[src + S]; v.z = x[src + 2 * S]; v.w = x[src + 3 * S];
  } else {
    const float* x = (const float*)xv;
    v.x = f2bf(x[src]); v.y = f2bf(x[src + S]);
    v.z = f2bf(x[src + 2 * S]); v.w = f2bf(x[src + 3 * S]);
  }
  *(ushort4*)(H + (size_t)r * CC + c4) = v;
}

// ---- Tx1[m] = H[m] - dis[m] * sum_e dis[col] * H[col]
__global__ __launch_bounds__(384) void k_spmm1(const unsigned short* __restrict__ H,
                                               const unsigned short* __restrict__ colidx,
                                               const int* __restrict__ deg,
                                               const float* __restrict__ dis,
                                               unsigned short* __restrict__ T1) {
  __shared__ int scol[MAXD];
  __shared__ float swt[MAXD];
  int m = blockIdx.x;
  int d = deg[m];
  float dm = dis[m];
  for (int j = threadIdx.x; j < d; j += 384) {
    int cc = (int)colidx[m * MAXD + j];
    scol[j] = cc;
    swt[j] = dis[cc];
  }
  __syncthreads();
  int j4 = threadIdx.x << 2;
  float a0 = 0.f, a1 = 0.f, a2 = 0.f, a3 = 0.f;
  #pragma unroll 4
  for (int e = 0; e < d; ++e) {
    float w = swt[e];
    uint2 hv = *(const uint2*)(H + (size_t)scol[e] * NC + j4);
    a0 = fmaf(w, blo(hv.x), a0);
    a1 = fmaf(w, bhi(hv.x), a1);
    a2 = fmaf(w, blo(hv.y), a2);
    a3 = fmaf(w, bhi(hv.y), a3);
  }
  uint2 hm = *(const uint2*)(H + (size_t)m * NC + j4);
  ushort4 o;
  o.x = f2bf(blo(hm.x) - dm * a0);
  o.y = f2bf(bhi(hm.x) - dm * a1);
  o.z = f2bf(blo(hm.y) - dm * a2);
  o.w = f2bf(bhi(hm.y) - dm * a3);
  *(ushort4*)(T1 + (size_t)m * NC + j4) = o;
}

// ---- Tx2 = 2*Tx1[m] - 2*dm*sum - H[m]; fused 32->32 channel mix + bias, write [B,32,N,T]
template<int BF16>
__global__ __launch_bounds__(384) void k_spmm2(const unsigned short* __restrict__ H,
                                               const unsigned short* __restrict__ T1,
                                               const unsigned short* __restrict__ colidx,
                                               const int* __restrict__ deg,
                                               const float* __restrict__ dis,
                                               const void* __restrict__ wgtv,
                                               const void* __restrict__ biasv,
                                               void* __restrict__ outv,
                                               const int* __restrict__ flag) {
  if ((*flag != 0) != (BF16 != 0)) return;
  __shared__ int scol[MAXD];
  __shared__ float swt[MAXD];
  __shared__ __align__(16) float sW[3 * CC * CC];  // [k][c][o]
  __shared__ float sB[CC];
  __shared__ __align__(16) float sH[BT * PAD];
  __shared__ __align__(16) float sP1[BT * PAD];
  __shared__ __align__(16) float sP2[BT * PAD];
  int m = blockIdx.x;
  int d = deg[m];
  float dm = dis[m];
  for (int i = threadIdx.x; i < 3 * CC * CC; i += 384) {
    sW[i] = BF16 ? bf2f(((const unsigned short*)wgtv)[i]) : ((const float*)wgtv)[i];
  }
  if (threadIdx.x < CC) {
    sB[threadIdx.x] = BF16 ? bf2f(((const unsigned short*)biasv)[threadIdx.x])
                           : ((const float*)biasv)[threadIdx.x];
  }
  for (int j = threadIdx.x; j < d; j += 384) {
    int cc = (int)colidx[m * MAXD + j];
    scol[j] = cc;
    swt[j] = dis[cc];
  }
  __syncthreads();
  int j4 = threadIdx.x << 2;
  float a0 = 0.f, a1 = 0.f, a2 = 0.f, a3 = 0.f;
  #pragma unroll 4
  for (int e = 0; e < d; ++e) {
    float w = swt[e];
    uint2 hv = *(const uint2*)(T1 + (size_t)scol[e] * NC + j4);
    a0 = fmaf(w, blo(hv.x), a0);
    a1 = fmaf(w, bhi(hv.x), a1);
    a2 = fmaf(w, blo(hv.y), a2);
    a3 = fmaf(w, bhi(hv.y), a3);
  }
  uint2 hm = *(const uint2*)(H + (size_t)m * NC + j4);
  uint2 tm = *(const uint2*)(T1 + (size_t)m * NC + j4);
  float h0 = blo(hm.x), h1 = bhi(hm.x), h2 = blo(hm.y), h3 = bhi(hm.y);
  float u0 = blo(tm.x), u1 = bhi(tm.x), u2 = blo(tm.y), u3 = bhi(tm.y);
  float td = 2.f * dm;
  int bt = j4 >> 5;
  int o0 = j4 & 31;             // doubles as c4 on the store side
  int base = bt * PAD + o0;
  *(float4*)&sH[base]  = make_float4(h0, h1, h2, h3);
  *(float4*)&sP1[base] = make_float4(u0, u1, u2, u3);
  *(float4*)&sP2[base] = make_float4(2.f * u0 - td * a0 - h0,
                                     2.f * u1 - td * a1 - h1,
                                     2.f * u2 - td * a2 - h2,
                                     2.f * u3 - td * a3 - h3);
  __syncthreads();
  float r0 = sB[o0], r1 = sB[o0 + 1], r2 = sB[o0 + 2], r3 = sB[o0 + 3];
  const float* hr = &sH[bt * PAD];
  const float* p1 = &sP1[bt * PAD];
  const float* p2 = &sP2[bt * PAD];
  #pragma unroll 8
  for (int c = 0; c < CC; ++c) {
    float hh = hr[c], q1 = p1[c], q2 = p2[c];
    float4 w0 = *(const float4*)&sW[(0 * CC + c) * CC + o0];
    float4 w1 = *(const float4*)&sW[(1 * CC + c) * CC + o0];
    float4 w2 = *(const float4*)&sW[(2 * CC + c) * CC + o0];
    r0 += hh * w0.x + q1 * w1.x + q2 * w2.x;
    r1 += hh * w0.y + q1 * w1.y + q2 * w2.y;
    r2 += hh * w0.z + q1 * w1.z + q2 * w2.z;
    r3 += hh * w0.w + q1 * w1.w + q2 * w2.w;
  }
  int b = bt / TT, t = bt - b * TT;
  const size_t S = (size_t)NN * TT;
  size_t ob = (((size_t)b * CC + o0) * NN + m) * TT + t;
  if (BF16) {
    unsigned short* out = (unsigned short*)outv;
    out[ob] = f2bf(r0); out[ob + S] = f2bf(r1);
    out[ob + 2 * S] = f2bf(r2); out[ob + 3 * S] = f2bf(r3);
  } else {
    float* out = (float*)outv;
    out[ob] = r0; out[ob + S] = r1;
    out[ob + 2 * S] = r2; out[ob + 3 * S] = r3;
  }
}

extern "C" void kernel_launch(void* const* d_in, const int* in_sizes, int n_in,
                              void* d_out, int out_size, void* d_ws, size_t ws_size,
                              hipStream_t stream) {
  const void* x    = d_in[0];
  const void* adj  = d_in[1];
  const void* wgt  = d_in[2];
  const void* bias = d_in[3];
  char* ws = (char*)d_ws;
  // ws layout (25.6 MB total):
  int*   flag = (int*)ws;                                      // 256 B
  float* dis  = (float*)(ws + 256);                            // 16 KB
  int*   deg  = (int*)(ws + 256 + 16384);                      // 16 KB
  unsigned short* colidx = (unsigned short*)(ws + 256 + 32768);            // 4096*192*2 = 1.5 MB
  unsigned short* H  = (unsigned short*)(ws + 256 + 32768 + 1572864);      // 12.6 MB
  unsigned short* T1 = (unsigned short*)(ws + 256 + 32768 + 1572864 + 12582912); // 12.6 MB

  k_detect<<<1, 64, 0, stream>>>((const unsigned int*)wgt, flag);
  k_build<1><<<NN, 256, 0, stream>>>(adj, colidx, deg, dis, flag);
  k_build<0><<<NN, 256, 0, stream>>>(adj, colidx, deg, dis, flag);
  k_trans<1><<<(NN * BT * 8) / 256, 256, 0, stream>>>(x, H, flag);
  k_trans<0><<<(NN * BT * 8) / 256, 256, 0, stream>>>(x, H, flag);
  k_spmm1<<<NN, 384, 0, stream>>>(H, colidx, deg, dis, T1);
  k_spmm2<1><<<NN, 384, 0, stream>>>(H, T1, colidx, deg, dis, wgt, bias, d_out, flag);
  k_spmm2<0><<<NN, 384, 0, stream>>>(H, T1, colidx, deg, dis, wgt, bias, d_out, flag);
}

// Round 2
// 317.900 us; speedup vs baseline: 1.2027x; 1.2027x over previous
//
#include <hip/hip_runtime.h>

#define NN 4096
#define CC 32
#define TT 12
#define BB 4
#define BT 48          // BB*TT
#define NC 1536        // BT*CC
#define MAXD 192       // mean degree ~82, P(deg>192) astronomically small
#define FW 256         // features per chunk = 8 bt * 32 c; chunk slice = 4096*512B = 2MB, L2-resident
#define NCH 6          // NC / FW
#define PADS 36        // padded bt-row stride for LDS mix staging (balanced banks, 16B-aligned)

__device__ __forceinline__ float bf2f(unsigned short h) {
  return __uint_as_float(((unsigned int)h) << 16);
}
__device__ __forceinline__ unsigned short f2bf(float f) {
  unsigned int u = __float_as_uint(f);
  return (unsigned short)((u + 0x7FFFu + ((u >> 16) & 1u)) >> 16);  // RNE
}
__device__ __forceinline__ float blo(unsigned int w) { return __uint_as_float(w << 16); }
__device__ __forceinline__ float bhi(unsigned int w) { return __uint_as_float(w & 0xFFFF0000u); }

// ---- dtype sniffing: bf16 halfwords have plausible exponent fields; fp32 low
// mantissa halfwords are ~uniform. 256 words of weight: bf16 -> ~256 hits,
// fp32 -> ~50 hits. Threshold 150.
__global__ void k_detect(const unsigned int* __restrict__ w, int* __restrict__ flag) {
  __shared__ int s;
  if (threadIdx.x == 0) s = 0;
  __syncthreads();
  int h = 0;
  for (int i = threadIdx.x; i < 256; i += 64) {
    unsigned int e = (w[i] >> 7) & 0xFFu;
    if (e >= 90u && e <= 141u) ++h;
  }
  atomicAdd(&s, h);
  __syncthreads();
  if (threadIdx.x == 0) *flag = (s >= 150) ? 1 : 0;
}

// ---- per-row adjacency compaction + degree + d^-1/2 (self-loops included)
template<int BF16>
__global__ __launch_bounds__(256) void k_build(const void* __restrict__ adjv,
                                               unsigned short* __restrict__ colidx,
                                               int* __restrict__ deg, float* __restrict__ dis,
                                               const int* __restrict__ flag) {
  if ((*flag != 0) != (BF16 != 0)) return;
  __shared__ int cnt;
  int m = blockIdx.x;
  if (threadIdx.x == 0) cnt = 0;
  __syncthreads();
  if (BF16) {
    const uint4* row = (const uint4*)((const unsigned short*)adjv + (size_t)m * NN);
    for (int i = threadIdx.x; i < NN / 8; i += 256) {
      uint4 v = row[i];
      unsigned int ws[4] = {v.x, v.y, v.z, v.w};
      #pragma unroll
      for (int k = 0; k < 4; ++k) {
        if (ws[k] & 0xFFFFu) {
          int p = atomicAdd(&cnt, 1);
          if (p < MAXD) colidx[m * MAXD + p] = (unsigned short)(i * 8 + k * 2);
        }
        if (ws[k] >> 16) {
          int p = atomicAdd(&cnt, 1);
          if (p < MAXD) colidx[m * MAXD + p] = (unsigned short)(i * 8 + k * 2 + 1);
        }
      }
    }
  } else {
    const uint4* row = (const uint4*)((const float*)adjv + (size_t)m * NN);
    for (int i = threadIdx.x; i < NN / 4; i += 256) {
      uint4 v = row[i];
      unsigned int ws[4] = {v.x, v.y, v.z, v.w};
      #pragma unroll
      for (int k = 0; k < 4; ++k) {
        if (ws[k] != 0) {
          int p = atomicAdd(&cnt, 1);
          if (p < MAXD) colidx[m * MAXD + p] = (unsigned short)(i * 4 + k);
        }
      }
    }
  }
  __syncthreads();
  if (threadIdx.x == 0) {
    int d = cnt < MAXD ? cnt : MAXD;
    deg[m] = d;
    dis[m] = d > 0 ? (float)(1.0 / sqrt((double)d)) : 0.0f;
  }
}

// ---- x[b][c][n][t] -> H[n][bt][c] (bf16), coalesced 8B writes
template<int BF16>
__global__ __launch_bounds__(256) void k_trans(const void* __restrict__ xv,
                                               unsigned short* __restrict__ H,
                                               const int* __restrict__ flag) {
  if ((*flag != 0) != (BF16 != 0)) return;
  int i = blockIdx.x * 256 + threadIdx.x;   // i < NN*BT*8
  int c4 = (i & 7) << 2;
  int r  = i >> 3;            // r = n*BT + bt
  int bt = r % BT;
  int b  = bt / TT;
  int t  = bt - b * TT;
  int n  = r / BT;
  const size_t S = (size_t)NN * TT;
  size_t src = ((((size_t)b * CC + c4) * NN + n) * TT + t);
  ushort4 v;
  if (BF16) {
    const unsigned short* x = (const unsigned short*)xv;
    v.x = x[src]; v.y = x[src + S]; v.z = x[src + 2 * S]; v.w = x[src + 3 * S];
  } else {
    const float* x = (const float*)xv;
    v.x = f2bf(x[src]); v.y = f2bf(x[src + S]);
    v.z = f2bf(x[src + 2 * S]); v.w = f2bf(x[src + 3 * S]);
  }
  *(ushort4*)(H + (size_t)r * CC + c4) = v;
}

// ---- chunked: Tx1[m, chunk] = H[m] - dis[m] * sum_e dis[col] * H[col]
// block = 256 thr = 4 waves; wave w handles node m = bx*4+w, chunk q = by.
__global__ __launch_bounds__(256) void k_spmm1(const unsigned short* __restrict__ H,
                                               const unsigned short* __restrict__ colidx,
                                               const int* __restrict__ deg,
                                               const float* __restrict__ dis,
                                               unsigned short* __restrict__ T1) {
  __shared__ int scol[4][MAXD];
  __shared__ float swt[4][MAXD];
  int wid = threadIdx.x >> 6, lane = threadIdx.x & 63;
  int m = blockIdx.x * 4 + wid;
  int q = blockIdx.y;
  int d = deg[m];
  float dm = dis[m];
  for (int j = lane; j < d; j += 64) {
    int cc = (int)colidx[m * MAXD + j];
    scol[wid][j] = cc;
    swt[wid][j] = dis[cc];
  }
  __syncthreads();
  size_t fo = (size_t)q * FW + (lane << 2);  // feature offset within row
  float a0 = 0.f, a1 = 0.f, a2 = 0.f, a3 = 0.f;
  #pragma unroll 4
  for (int e = 0; e < d; ++e) {
    float w = swt[wid][e];
    uint2 hv = *(const uint2*)(H + (size_t)scol[wid][e] * NC + fo);
    a0 = fmaf(w, blo(hv.x), a0);
    a1 = fmaf(w, bhi(hv.x), a1);
    a2 = fmaf(w, blo(hv.y), a2);
    a3 = fmaf(w, bhi(hv.y), a3);
  }
  uint2 hm = *(const uint2*)(H + (size_t)m * NC + fo);
  ushort4 o;
  o.x = f2bf(blo(hm.x) - dm * a0);
  o.y = f2bf(bhi(hm.x) - dm * a1);
  o.z = f2bf(blo(hm.y) - dm * a2);
  o.w = f2bf(bhi(hm.y) - dm * a3);
  *(ushort4*)(T1 + (size_t)m * NC + fo) = o;
}

// ---- chunked: Tx2 = 2*Tx1[m] - 2*dm*sum - H[m]; fused 32->32 channel mix + bias,
// write [B,32,N,T]. Wave w handles node m = bx*4+w, chunk q = by (8 bt * 32 c).
template<int BF16>
__global__ __launch_bounds__(256) void k_spmm2(const unsigned short* __restrict__ H,
                                               const unsigned short* __restrict__ T1,
                                               const unsigned short* __restrict__ colidx,
                                               const int* __restrict__ deg,
                                               const float* __restrict__ dis,
                                               const void* __restrict__ wgtv,
                                               const void* __restrict__ biasv,
                                               void* __restrict__ outv,
                                               const int* __restrict__ flag) {
  if ((*flag != 0) != (BF16 != 0)) return;
  __shared__ int scol[4][MAXD];
  __shared__ float swt[4][MAXD];
  __shared__ __align__(16) float sW[3 * CC * CC];  // [k][c][o]
  __shared__ float sB[CC];
  __shared__ __align__(16) float sH[4][8 * PADS];
  __shared__ __align__(16) float sP1[4][8 * PADS];
  __shared__ __align__(16) float sP2[4][8 * PADS];
  int wid = threadIdx.x >> 6, lane = threadIdx.x & 63;
  int m = blockIdx.x * 4 + wid;
  int q = blockIdx.y;
  int d = deg[m];
  float dm = dis[m];
  for (int i = threadIdx.x; i < 3 * CC * CC; i += 256) {
    sW[i] = BF16 ? bf2f(((const unsigned short*)wgtv)[i]) : ((const float*)wgtv)[i];
  }
  if (threadIdx.x < CC) {
    sB[threadIdx.x] = BF16 ? bf2f(((const unsigned short*)biasv)[threadIdx.x])
                           : ((const float*)biasv)[threadIdx.x];
  }
  for (int j = lane; j < d; j += 64) {
    int cc = (int)colidx[m * MAXD + j];
    scol[wid][j] = cc;
    swt[wid][j] = dis[cc];
  }
  __syncthreads();
  size_t fo = (size_t)q * FW + (lane << 2);
  float a0 = 0.f, a1 = 0.f, a2 = 0.f, a3 = 0.f;
  #pragma unroll 4
  for (int e = 0; e < d; ++e) {
    float w = swt[wid][e];
    uint2 hv = *(const uint2*)(T1 + (size_t)scol[wid][e] * NC + fo);
    a0 = fmaf(w, blo(hv.x), a0);
    a1 = fmaf(w, bhi(hv.x), a1);
    a2 = fmaf(w, blo(hv.y), a2);
    a3 = fmaf(w, bhi(hv.y), a3);
  }
  uint2 hm = *(const uint2*)(H + (size_t)m * NC + fo);
  uint2 tm = *(const uint2*)(T1 + (size_t)m * NC + fo);
  float h0 = blo(hm.x), h1 = bhi(hm.x), h2 = blo(hm.y), h3 = bhi(hm.y);
  float u0 = blo(tm.x), u1 = bhi(tm.x), u2 = blo(tm.y), u3 = bhi(tm.y);
  float td = 2.f * dm;
  int btl = lane >> 3;           // bt within chunk [0,8)
  int o0  = (lane & 7) << 2;     // channel group; doubles as c4 on store side
  int base = btl * PADS + o0;
  *(float4*)&sH[wid][base]  = make_float4(h0, h1, h2, h3);
  *(float4*)&sP1[wid][base] = make_float4(u0, u1, u2, u3);
  *(float4*)&sP2[wid][base] = make_float4(2.f * u0 - td * a0 - h0,
                                          2.f * u1 - td * a1 - h1,
                                          2.f * u2 - td * a2 - h2,
                                          2.f * u3 - td * a3 - h3);
  __syncthreads();
  float r0 = sB[o0], r1 = sB[o0 + 1], r2 = sB[o0 + 2], r3 = sB[o0 + 3];
  const float* hr = &sH[wid][btl * PADS];
  const float* p1 = &sP1[wid][btl * PADS];
  const float* p2 = &sP2[wid][btl * PADS];
  #pragma unroll 8
  for (int c = 0; c < CC; ++c) {
    float hh = hr[c], q1 = p1[c], q2 = p2[c];
    float4 w0 = *(const float4*)&sW[(0 * CC + c) * CC + o0];
    float4 w1 = *(const float4*)&sW[(1 * CC + c) * CC + o0];
    float4 w2 = *(const float4*)&sW[(2 * CC + c) * CC + o0];
    r0 += hh * w0.x + q1 * w1.x + q2 * w2.x;
    r1 += hh * w0.y + q1 * w1.y + q2 * w2.y;
    r2 += hh * w0.z + q1 * w1.z + q2 * w2.z;
    r3 += hh * w0.w + q1 * w1.w + q2 * w2.w;
  }
  int bt = q * 8 + btl;
  int b = bt / TT, t = bt - b * TT;
  const size_t S = (size_t)NN * TT;
  size_t ob = (((size_t)b * CC + o0) * NN + m) * TT + t;
  if (BF16) {
    unsigned short* out = (unsigned short*)outv;
    out[ob] = f2bf(r0); out[ob + S] = f2bf(r1);
    out[ob + 2 * S] = f2bf(r2); out[ob + 3 * S] = f2bf(r3);
  } else {
    float* out = (float*)outv;
    out[ob] = r0; out[ob + S] = r1;
    out[ob + 2 * S] = r2; out[ob + 3 * S] = r3;
  }
}

extern "C" void kernel_launch(void* const* d_in, const int* in_sizes, int n_in,
                              void* d_out, int out_size, void* d_ws, size_t ws_size,
                              hipStream_t stream) {
  const void* x    = d_in[0];
  const void* adj  = d_in[1];
  const void* wgt  = d_in[2];
  const void* bias = d_in[3];
  char* ws = (char*)d_ws;
  // ws layout (~27 MB total):
  int*   flag = (int*)ws;                                      // 256 B
  float* dis  = (float*)(ws + 256);                            // 16 KB
  int*   deg  = (int*)(ws + 256 + 16384);                      // 16 KB
  unsigned short* colidx = (unsigned short*)(ws + 256 + 32768);            // 4096*192*2 = 1.5 MB
  unsigned short* H  = (unsigned short*)(ws + 256 + 32768 + 1572864);      // 12.6 MB
  unsigned short* T1 = (unsigned short*)(ws + 256 + 32768 + 1572864 + 12582912); // 12.6 MB

  k_detect<<<1, 64, 0, stream>>>((const unsigned int*)wgt, flag);
  k_build<1><<<NN, 256, 0, stream>>>(adj, colidx, deg, dis, flag);
  k_build<0><<<NN, 256, 0, stream>>>(adj, colidx, deg, dis, flag);
  k_trans<1><<<(NN * BT * 8) / 256, 256, 0, stream>>>(x, H, flag);
  k_trans<0><<<(NN * BT * 8) / 256, 256, 0, stream>>>(x, H, flag);
  k_spmm1<<<dim3(NN / 4, NCH), 256, 0, stream>>>(H, colidx, deg, dis, T1);
  k_spmm2<1><<<dim3(NN / 4, NCH), 256, 0, stream>>>(H, T1, colidx, deg, dis, wgt, bias, d_out, flag);
  k_spmm2<0><<<dim3(NN / 4, NCH), 256, 0, stream>>>(H, T1, colidx, deg, dis, wgt, bias, d_out, flag);
}